// Round 9
// baseline (115.713 us; speedup 1.0000x reference)
//
#include <hip/hip_runtime.h>

// DiscriminativeLoss: data [32, 512, 1024] f32 (D-planar), labels [512,1024] i32 in [0,16)
// out: scalar f32 loss.
//
// Lessons:
//  - LDS float atomicAdd ~300 cyc/wave-instr on gfx950 -> never in hot loop.
//  - grid.sync() cooperative: ~150us stall -> dead. Kernel boundary is the cheap barrier.
//  - Harness reset (268 MB ws fill ~43us + d_in restore ~21us) ~72us fixed in-window.
//  - Round 7: kB pass-2 is fully L3-fed (hbm_bytes~16KB), 11.7us/rep at 5.7 TB/s.
//  - Round 8: no-alias column rotation (component c -> column (t+64c)&255; residues
//    pairwise distinct mod 256 for ANY labels) broke the 4x LDS round-trip chain: -7us.
//  - THIS ROUND: occupancy. kA: 16KB LDS (cnt moved to 32 dedicated count-blocks),
//    2048+32 blocks -> 8 blocks/CU, 32 waves/CU. kB: d-split halves -> 1024 blocks,
//    16 waves/CU. kA epilogue -> padded global atomicAdd (tiny memset node) so kB's
//    prologue is a 530-float read instead of a 128KB reduction.
//
// ws float layout (64 B padded atomic slots):
//   sums[(k*32 + d)*16] : [0, 8192)
//   cnts[k*16]          : [8192, 8448)

constexpr int KC = 16;
constexpr int DD = 32;
constexpr int NN = 512 * 1024;
constexpr int N4 = NN / 4;               // 131072 float4 groups per d-plane
constexpr int CHUNKS = 64;
constexpr int GPC = N4 / CHUNKS;         // 2048 groups per chunk
constexpr int AITERS = GPC / 256;        // 8
constexpr int NDATA = CHUNKS * DD;       // 2048 data blocks
constexpr int NCNT = 32;                 // count blocks
constexpr int CITERS = N4 / NCNT / 256;  // 16

constexpr int WS_SUM = 0;
constexpr int WS_CNT = 8192;
constexpr int WS_ZERO_FLOATS = 8448;

__global__ __launch_bounds__(256) void kA_sums(const float4* __restrict__ data4,
                                               const int4* __restrict__ lab4,
                                               float* __restrict__ ws,
                                               float* __restrict__ out) {
    const int tid = threadIdx.x;
    const int bid = blockIdx.x;

    if (bid == 0 && tid == 0) out[0] = 0.f;          // kB atomicAdds on top

    // acc[k*256 + col]: component c of thread t uses col (t+64c)&255 -> 4 RMW targets
    // pairwise distinct for ANY labels -> hoisted reads, 1 LDS latency per iter.
    // Bank = col%32 = tid%32 -> deterministic 2-way (free). 16 KB -> 8 blocks/CU.
    __shared__ float acc[KC * 256];
#pragma unroll
    for (int k = 0; k < KC; ++k) acc[k * 256 + tid] = 0.f;
    __syncthreads();

    const int c0 = tid;
    const int c1 = (tid + 64) & 255;
    const int c2 = (tid + 128) & 255;
    const int c3 = (tid + 192) & 255;

    if (bid < NDATA) {
        // ---- data block: per-cluster sums for one (chunk, d) ----
        const int chunk = bid & (CHUNKS - 1);
        const int d = bid >> 6;
        const float4* dplane = data4 + (size_t)d * N4;
        int g = chunk * GPC + tid;

        float4 v = dplane[g];
        int4 lb = lab4[g];
        for (int it = 0; it < AITERS; ++it) {
            float4 vn;
            int4 lbn;
            if (it + 1 < AITERS) {
                vn = dplane[g + 256];
                lbn = lab4[g + 256];
            }
            const int i0 = lb.x * 256 + c0;
            const int i1 = lb.y * 256 + c1;
            const int i2 = lb.z * 256 + c2;
            const int i3 = lb.w * 256 + c3;
            const float a0 = acc[i0];
            const float a1 = acc[i1];
            const float a2 = acc[i2];
            const float a3 = acc[i3];
            acc[i0] = a0 + v.x;
            acc[i1] = a1 + v.y;
            acc[i2] = a2 + v.z;
            acc[i3] = a3 + v.w;
            v = vn;
            lb = lbn;
            g += 256;
        }
        __syncthreads();

        const int k = tid >> 4, seg = tid & 15;
        float s = 0.f;
#pragma unroll
        for (int i = 0; i < 16; ++i) s += acc[k * 256 + seg * 16 + i];
#pragma unroll
        for (int off = 8; off > 0; off >>= 1) s += __shfl_down(s, off, 16);
        if (seg == 0) atomicAdd(&ws[WS_SUM + (k * DD + d) * 16], s);
    } else {
        // ---- count block: label histogram only (labels 2 MB, L2/L3-hot) ----
        const int cb = bid - NDATA;
        int g = cb * (N4 / NCNT) + tid;

        int4 lb = lab4[g];
        for (int it = 0; it < CITERS; ++it) {
            int4 lbn;
            if (it + 1 < CITERS) lbn = lab4[g + 256];
            const int i0 = lb.x * 256 + c0;
            const int i1 = lb.y * 256 + c1;
            const int i2 = lb.z * 256 + c2;
            const int i3 = lb.w * 256 + c3;
            const float a0 = acc[i0];
            const float a1 = acc[i1];
            const float a2 = acc[i2];
            const float a3 = acc[i3];
            acc[i0] = a0 + 1.f;
            acc[i1] = a1 + 1.f;
            acc[i2] = a2 + 1.f;
            acc[i3] = a3 + 1.f;
            lb = lbn;
            g += 256;
        }
        __syncthreads();

        const int k = tid >> 4, seg = tid & 15;
        float c = 0.f;
#pragma unroll
        for (int i = 0; i < 16; ++i) c += acc[k * 256 + seg * 16 + i];
#pragma unroll
        for (int off = 8; off > 0; off >>= 1) c += __shfl_down(c, off, 16);
        if (seg == 0) atomicAdd(&ws[WS_CNT + k * 16], c);
    }
}

__global__ __launch_bounds__(256) void kB_var(const float4* __restrict__ data4,
                                              const int4* __restrict__ lab4,
                                              const float* __restrict__ ws,
                                              float* __restrict__ out) {
    __shared__ float csum[512];
    __shared__ float ccnt[KC];
    __shared__ float ct2[DD * 32];       // centers_t duplicated (k, k+16)
    __shared__ float sh[4][128];
    __shared__ float wred[4];
    const int tid = threadIdx.x;

    // Tiny center build (530 strided floats from L2).
    if (tid < KC) ccnt[tid] = ws[WS_CNT + tid * 16];
    csum[tid] = ws[WS_SUM + tid * 16];
    csum[tid + 256] = ws[WS_SUM + (tid + 256) * 16];
    __syncthreads();
    for (int idx = tid; idx < KC * DD; idx += 256) {
        const int k = idx >> 5, d = idx & 31;
        const float c = csum[idx] / ccnt[k];       // slot = k*32+d = idx
        ct2[d * 32 + k] = c;
        ct2[d * 32 + 16 + k] = c;
    }
    __syncthreads();

    // Dist + reg terms: block 0 only.
    if (blockIdx.x == 0) {
        const int i = tid >> 4, j = tid & 15;
        float val;
        if (i != j) {
            float sq = 0.f;
#pragma unroll
            for (int d = 0; d < DD; ++d) {
                const float df = ct2[d * 32 + i] - ct2[d * 32 + j];
                sq += df * df;
            }
            const float pd = sqrtf(sq);
            const float t = fmaxf(3.0f - pd, 0.f);            // 2*DELTA_DIST
            val = t * t * (1.0f / (KC * (KC - 1)));
        } else {
            float s2 = 0.f;
#pragma unroll
            for (int d = 0; d < DD; ++d) s2 += ct2[d * 32 + i] * ct2[d * 32 + i];
            val = sqrtf(s2) * (0.001f / KC);                   // reg term
        }
        __shared__ float red[256];
        red[tid] = val;
        __syncthreads();
        for (int off = 128; off > 0; off >>= 1) {
            if (tid < off) red[tid] += red[tid + off];
            __syncthreads();
        }
        if (tid == 0) atomicAdd(out, red[0]);
        __syncthreads();
    }

    // Pass 2, d-split: threads t and t+128 share float4 group g, halves of d-range.
    // 1024 blocks x 256 -> 4 blocks/CU, 16 waves/CU (2x round-8 kB occupancy).
    const int t = tid & 127, half = tid >> 7;
    const int g = blockIdx.x * 128 + t;
    const int4 lb = lab4[g];
    const int dup = (tid & 32) >> 1;     // half the lanes read the +16 duplicate
    const int o0 = lb.x + dup, o1 = lb.y + dup, o2 = lb.z + dup, o3 = lb.w + dup;

    float s0 = 0.f, s1 = 0.f, s2 = 0.f, s3 = 0.f;
    const int dbase = half * 16;
#pragma unroll
    for (int i = 0; i < 16; ++i) {
        const int dd = dbase + i;
        const float4 v = data4[(size_t)dd * N4 + g];
        const float* ctd = ct2 + dd * 32;
        const float d0 = ctd[o0] - v.x; s0 += d0 * d0;
        const float d1 = ctd[o1] - v.y; s1 += d1 * d1;
        const float d2 = ctd[o2] - v.z; s2 += d2 * d2;
        const float d3 = ctd[o3] - v.w; s3 += d3 * d3;
    }
    if (half) {
        sh[0][t] = s0;
        sh[1][t] = s1;
        sh[2][t] = s2;
        sh[3][t] = s3;
    }
    __syncthreads();
    float lsum = 0.f;
    if (!half) {
        s0 += sh[0][t];
        s1 += sh[1][t];
        s2 += sh[2][t];
        s3 += sh[3][t];
        const float h0 = fmaxf(sqrtf(s0) - 0.5f, 0.f);
        const float h1 = fmaxf(sqrtf(s1) - 0.5f, 0.f);
        const float h2 = fmaxf(sqrtf(s2) - 0.5f, 0.f);
        const float h3 = fmaxf(sqrtf(s3) - 0.5f, 0.f);
        lsum = h0 * h0 + h1 * h1 + h2 * h2 + h3 * h3;
    }
#pragma unroll
    for (int off = 32; off > 0; off >>= 1) lsum += __shfl_down(lsum, off);
    if ((tid & 63) == 0) wred[tid >> 6] = lsum;
    __syncthreads();
    if (tid == 0) {
        const float s = wred[0] + wred[1] + wred[2] + wred[3];
        atomicAdd(out, s * (1.0f / KC));
    }
}

extern "C" void kernel_launch(void* const* d_in, const int* in_sizes, int n_in,
                              void* d_out, int out_size, void* d_ws, size_t ws_size,
                              hipStream_t stream) {
    const float4* data4 = (const float4*)d_in[0];
    const int4* lab4 = (const int4*)d_in[1];
    float* out = (float*)d_out;
    float* ws = (float*)d_ws;

    hipMemsetAsync(ws, 0, WS_ZERO_FLOATS * sizeof(float), stream);
    kA_sums<<<NDATA + NCNT, 256, 0, stream>>>(data4, lab4, ws, out);
    kB_var<<<N4 / 128, 256, 0, stream>>>(data4, lab4, ws, out);
}

// Round 11
// 112.207 us; speedup vs baseline: 1.0312x; 1.0312x over previous
//
#include <hip/hip_runtime.h>

// DiscriminativeLoss: data [32, 512, 1024] f32 (D-planar), labels [512,1024] i32 in [0,16)
// out: scalar f32 loss.
//
// Lessons:
//  - LDS float atomicAdd ~300 cyc/wave-instr on gfx950 -> never in hot loop.
//  - grid.sync() cooperative: ~150us stall -> dead. Kernel boundary is the cheap barrier.
//  - Harness reset (268 MB ws fill ~43us + d_in restore) ~72us fixed inside the window.
//  - R7 measurement: kB pass-2 fully L3-fed (hbm_bytes~16KB), 11.7us at the per-CU
//    vector-load issue cap -> kB done. kA cold ~16-20us vs ~11us floor.
//  - R8: no-alias column rotation broke the 4x LDS round-trip chain: -7us (111.9 best).
//  - R9 bundle (8-iter blocks + global-atomic epilogue + kB d-split): -3.8us regression.
//  - R10: container infra failure; this is the identical kernel resubmitted.
//  - THIS ROUND (delta from R8 only in kA): drop cnt from data blocks (halves LDS-pipe
//    load - cnt RMWs were equal traffic to acc); 2 float4 groups/thread/iter with
//    disjoint column sets {t+64c} and {t+32+64c} (8 residues pairwise distinct mod 256
//    for ANY labels -> 8 independent hoisted reads, 1 wait); counts from 16 label-only
//    blocks (labels 2MB, L2-hot). kB = R8's kB exactly (cpart reduce now over 16).
//
// ws float layout:
//   partials[(k*32 + d)*32 + chunk] : [0, 16384)
//   cpart[k*16 + cb]                : [16384, 16640)

constexpr int KC = 16;
constexpr int DD = 32;
constexpr int NN = 512 * 1024;
constexpr int N4 = NN / 4;             // 131072 float4 groups per d-plane
constexpr int CHUNKS = 32;
constexpr int GPC = N4 / CHUNKS;       // 4096 groups per chunk
constexpr int AITERS = GPC / 512;      // 8 (2 groups per thread per iter)
constexpr int NDATA = CHUNKS * DD;     // 1024 data blocks
constexpr int NCNT = 16;               // label-count blocks
constexpr int CGROUPS = N4 / NCNT;     // 8192
constexpr int CITERS = CGROUPS / 512;  // 16

constexpr int WS_P  = 0;
constexpr int WS_CP = 16384;

__global__ __launch_bounds__(256) void kA_sums(const float4* __restrict__ data4,
                                               const int4* __restrict__ lab4,
                                               float* __restrict__ ws,
                                               float* __restrict__ out) {
    const int tid = threadIdx.x;
    const int bid = blockIdx.x;

    if (bid == 0 && tid == 0) out[0] = 0.f;          // kB atomicAdds on top

    // acc[k*256 + col]. Columns for the two groups of thread t:
    //   A: (t+64c)&255, B: (t+32+64c)&255  -> 8 residues pairwise distinct mod 256
    // for ANY labels -> all 8 RMW targets distinct -> reads hoistable, 1 LDS wait/iter.
    // Bank = col%32 = tid%32 -> deterministic 2-way (free). 16 KB LDS.
    __shared__ float acc[KC * 256];
#pragma unroll
    for (int k = 0; k < KC; ++k) acc[k * 256 + tid] = 0.f;
    __syncthreads();

    const int cA0 = tid;
    const int cA1 = (tid + 64) & 255;
    const int cA2 = (tid + 128) & 255;
    const int cA3 = (tid + 192) & 255;
    const int cB0 = (tid + 32) & 255;
    const int cB1 = (tid + 96) & 255;
    const int cB2 = (tid + 160) & 255;
    const int cB3 = (tid + 224) & 255;

    if (bid < NDATA) {
        // ---- data block: per-cluster sums for one (chunk, d), no counting ----
        const int chunk = bid & (CHUNKS - 1);
        const int d = bid >> 5;
        const float4* dplane = data4 + (size_t)d * N4;
        int g = chunk * GPC + tid;

        float4 va = dplane[g], vb = dplane[g + 256];
        int4 la = lab4[g], lbv = lab4[g + 256];
        for (int it = 0; it < AITERS; ++it) {
            float4 van, vbn;
            int4 lan, lbn;
            if (it + 1 < AITERS) {
                van = dplane[g + 512];
                vbn = dplane[g + 768];
                lan = lab4[g + 512];
                lbn = lab4[g + 768];
            }
            const int iA0 = la.x * 256 + cA0;
            const int iA1 = la.y * 256 + cA1;
            const int iA2 = la.z * 256 + cA2;
            const int iA3 = la.w * 256 + cA3;
            const int iB0 = lbv.x * 256 + cB0;
            const int iB1 = lbv.y * 256 + cB1;
            const int iB2 = lbv.z * 256 + cB2;
            const int iB3 = lbv.w * 256 + cB3;
            // 8 independent reads (distinct by construction), then 8 writes.
            const float a0 = acc[iA0];
            const float a1 = acc[iA1];
            const float a2 = acc[iA2];
            const float a3 = acc[iA3];
            const float b0 = acc[iB0];
            const float b1 = acc[iB1];
            const float b2 = acc[iB2];
            const float b3 = acc[iB3];
            acc[iA0] = a0 + va.x;
            acc[iA1] = a1 + va.y;
            acc[iA2] = a2 + va.z;
            acc[iA3] = a3 + va.w;
            acc[iB0] = b0 + vb.x;
            acc[iB1] = b1 + vb.y;
            acc[iB2] = b2 + vb.z;
            acc[iB3] = b3 + vb.w;
            va = van; vb = vbn; la = lan; lbv = lbn;
            g += 512;
        }
        __syncthreads();

        const int k = tid >> 4, seg = tid & 15;
        float s = 0.f;
#pragma unroll
        for (int i = 0; i < 16; ++i) s += acc[k * 256 + seg * 16 + i];
#pragma unroll
        for (int off = 8; off > 0; off >>= 1) s += __shfl_down(s, off, 16);
        if (seg == 0) ws[WS_P + (k * DD + d) * CHUNKS + chunk] = s;   // plain store
    } else {
        // ---- count block: label histogram only (labels 2 MB, L2-hot) ----
        const int cb = bid - NDATA;
        int g = cb * CGROUPS + tid;

        int4 la = lab4[g], lbv = lab4[g + 256];
        for (int it = 0; it < CITERS; ++it) {
            int4 lan, lbn;
            if (it + 1 < CITERS) {
                lan = lab4[g + 512];
                lbn = lab4[g + 768];
            }
            const int iA0 = la.x * 256 + cA0;
            const int iA1 = la.y * 256 + cA1;
            const int iA2 = la.z * 256 + cA2;
            const int iA3 = la.w * 256 + cA3;
            const int iB0 = lbv.x * 256 + cB0;
            const int iB1 = lbv.y * 256 + cB1;
            const int iB2 = lbv.z * 256 + cB2;
            const int iB3 = lbv.w * 256 + cB3;
            const float a0 = acc[iA0];
            const float a1 = acc[iA1];
            const float a2 = acc[iA2];
            const float a3 = acc[iA3];
            const float b0 = acc[iB0];
            const float b1 = acc[iB1];
            const float b2 = acc[iB2];
            const float b3 = acc[iB3];
            acc[iA0] = a0 + 1.f;
            acc[iA1] = a1 + 1.f;
            acc[iA2] = a2 + 1.f;
            acc[iA3] = a3 + 1.f;
            acc[iB0] = b0 + 1.f;
            acc[iB1] = b1 + 1.f;
            acc[iB2] = b2 + 1.f;
            acc[iB3] = b3 + 1.f;
            la = lan; lbv = lbn;
            g += 512;
        }
        __syncthreads();

        const int k = tid >> 4, seg = tid & 15;
        float c = 0.f;
#pragma unroll
        for (int i = 0; i < 16; ++i) c += acc[k * 256 + seg * 16 + i];
#pragma unroll
        for (int off = 8; off > 0; off >>= 1) c += __shfl_down(c, off, 16);
        if (seg == 0) ws[WS_CP + k * NCNT + cb] = c;                  // plain store
    }
}

__global__ __launch_bounds__(256) void kB_var(const float4* __restrict__ data4,
                                              const int4* __restrict__ lab4,
                                              const float* __restrict__ ws,
                                              float* __restrict__ out) {
    __shared__ float csum[KC * 33];
    __shared__ float ccnt[KC];
    __shared__ float ct2[DD * 32];       // centers_t duplicated (k, k+16)
    const int tid = threadIdx.x;

    // Redundant per-block center build (partials 66 KB, L2/L3-resident).
    {
        int idx = tid;
        const float* p = ws + WS_P + idx * CHUNKS;
        float s = 0.f;
#pragma unroll
        for (int c = 0; c < CHUNKS; ++c) s += p[c];
        csum[(idx >> 5) * 33 + (idx & 31)] = s;
        idx = tid + 256;
        p = ws + WS_P + idx * CHUNKS;
        s = 0.f;
#pragma unroll
        for (int c = 0; c < CHUNKS; ++c) s += p[c];
        csum[(idx >> 5) * 33 + (idx & 31)] = s;
    }
    if (tid < KC) {
        const float* p = ws + WS_CP + tid * NCNT;
        float c = 0.f;
#pragma unroll
        for (int i = 0; i < NCNT; ++i) c += p[i];
        ccnt[tid] = c;
    }
    __syncthreads();

    for (int idx = tid; idx < KC * DD; idx += 256) {
        const int k = idx >> 5, d = idx & 31;
        const float c = csum[k * 33 + d] / ccnt[k];
        ct2[d * 32 + k] = c;
        ct2[d * 32 + 16 + k] = c;
    }
    __syncthreads();

    // Dist + reg terms: block 0 only.
    if (blockIdx.x == 0) {
        const int i = tid >> 4, j = tid & 15;
        float val;
        if (i != j) {
            float sq = 0.f;
#pragma unroll
            for (int d = 0; d < DD; ++d) {
                const float df = ct2[d * 32 + i] - ct2[d * 32 + j];
                sq += df * df;
            }
            const float pd = sqrtf(sq);
            const float t = fmaxf(3.0f - pd, 0.f);            // 2*DELTA_DIST
            val = t * t * (1.0f / (KC * (KC - 1)));
        } else {
            float s2 = 0.f;
#pragma unroll
            for (int d = 0; d < DD; ++d) s2 += ct2[d * 32 + i] * ct2[d * 32 + i];
            val = sqrtf(s2) * (0.001f / KC);                   // reg term
        }
        __shared__ float red[256];
        red[tid] = val;
        __syncthreads();
        for (int off = 128; off > 0; off >>= 1) {
            if (tid < off) red[tid] += red[tid + off];
            __syncthreads();
        }
        if (tid == 0) atomicAdd(out, red[0]);
        __syncthreads();
    }

    // Pass 2: one float4 group per thread (512 blocks x 256 = N4). L3-fed, ~11.7us.
    const int g = blockIdx.x * 256 + tid;
    const int4 lb = lab4[g];
    const int dup = (tid & 32) >> 1;     // lanes 32-63 read the +16 duplicate
    const int o0 = lb.x + dup, o1 = lb.y + dup, o2 = lb.z + dup, o3 = lb.w + dup;

    float s0 = 0.f, s1 = 0.f, s2 = 0.f, s3 = 0.f;
#pragma unroll 8
    for (int d = 0; d < DD; ++d) {
        const float4 v = data4[(size_t)d * N4 + g];
        const float* ctd = ct2 + d * 32;
        const float d0 = ctd[o0] - v.x; s0 += d0 * d0;
        const float d1 = ctd[o1] - v.y; s1 += d1 * d1;
        const float d2 = ctd[o2] - v.z; s2 += d2 * d2;
        const float d3 = ctd[o3] - v.w; s3 += d3 * d3;
    }
    const float h0 = fmaxf(sqrtf(s0) - 0.5f, 0.f);
    const float h1 = fmaxf(sqrtf(s1) - 0.5f, 0.f);
    const float h2 = fmaxf(sqrtf(s2) - 0.5f, 0.f);
    const float h3 = fmaxf(sqrtf(s3) - 0.5f, 0.f);
    float lsum = h0 * h0 + h1 * h1 + h2 * h2 + h3 * h3;

#pragma unroll
    for (int off = 32; off > 0; off >>= 1) lsum += __shfl_down(lsum, off);
    __shared__ float wred[4];
    if ((tid & 63) == 0) wred[tid >> 6] = lsum;
    __syncthreads();
    if (tid == 0) {
        const float s = wred[0] + wred[1] + wred[2] + wred[3];
        atomicAdd(out, s * (1.0f / KC));
    }
}

extern "C" void kernel_launch(void* const* d_in, const int* in_sizes, int n_in,
                              void* d_out, int out_size, void* d_ws, size_t ws_size,
                              hipStream_t stream) {
    const float4* data4 = (const float4*)d_in[0];
    const int4* lab4 = (const int4*)d_in[1];
    float* out = (float*)d_out;
    float* ws = (float*)d_ws;

    kA_sums<<<NDATA + NCNT, 256, 0, stream>>>(data4, lab4, ws, out);
    kB_var<<<512, 256, 0, stream>>>(data4, lab4, ws, out);
}